// Round 2
// baseline (233.364 us; speedup 1.0000x reference)
//
#include <hip/hip_runtime.h>
#include <cstdint>

constexpr int GN  = 41;                 // grid points per dim
constexpr int VOX = GN * GN * GN;       // 68921 spatial points
constexpr int CH  = 32;                 // channels
constexpr int EF  = 128;                // encoder features

// -------- Pass 1: transpose grid [C][X][Y][Z] -> [X][Y][Z][C] into d_ws ----
// thread = spatial point s: 32 coalesced reads (lanes consecutive in s),
// one 128B contiguous vectorized write per thread.
__global__ __launch_bounds__(256) void transpose_grid_k(
    const float* __restrict__ src, float* __restrict__ dst) {
    int s = blockIdx.x * 256 + threadIdx.x;
    if (s >= VOX) return;
    float v[CH];
#pragma unroll
    for (int c = 0; c < CH; ++c) v[c] = src[c * VOX + s];
    float4* d4 = reinterpret_cast<float4*>(dst + (size_t)s * CH);
#pragma unroll
    for (int q = 0; q < 8; ++q)
        d4[q] = make_float4(v[4 * q], v[4 * q + 1], v[4 * q + 2], v[4 * q + 3]);
}

__device__ __forceinline__ void bspline_w(float t, float w[4]) {
    float t2 = t * t, t3 = t2 * t;
    const float k = 1.0f / 6.0f;
    w[0] = k * (1.0f - 3.0f * t + 3.0f * t2 - t3);
    w[1] = k * (4.0f - 6.0f * t2 + 3.0f * t3);
    w[2] = k * (1.0f + 3.0f * t + 3.0f * t2 - 3.0f * t3);
    w[3] = k * t3;
}

// -------- Pass 2: two elements per wave -----------------------------------
// lane = half(1b) | zsl(2b) | cquad(3b):
//   half = lane>>5 selects element of the pair
//   zsl  = (lane&31)>>3 = z tap 0..3
//   cq   = (lane&7)*4   = channel quad
// Gather: one float4 per lane per (i,j) row; 32 lanes x 16B = 512B chunk per
// element, both elements in one dwordx4 instruction.
// enc_w lives in LDS transposed: ewT[k][f], f=lane and f=lane+64 per lane ->
// bank = (k*128 + f) % 32 = f % 32: lanes 0..63 -> 2-way (free) conflicts.
__global__ __launch_bounds__(256, 4) void lig_main(
    const float* __restrict__ nb, const float* __restrict__ gT,
    const float* __restrict__ enc_w, const float* __restrict__ enc_b,
    float* __restrict__ out, int batch) {

    __shared__ float ewT[CH * EF];      // 16 KB: ewT[k*128 + f] = enc_w[f*32+k]
    for (int idx = threadIdx.x; idx < CH * EF; idx += 256) {
        int f = idx >> 5, k = idx & 31;
        ewT[k * EF + f] = enc_w[idx];   // coalesced global read
    }
    __syncthreads();

    const int lane = threadIdx.x & 63;
    const int half = lane >> 5;
    const int ln32 = lane & 31;
    const int zsl  = ln32 >> 3;
    const int cq   = (ln32 & 7) * 4;
    const int wid  = blockIdx.x * (blockDim.x >> 6) + (threadIdx.x >> 6);
    const int nw   = gridDim.x * (blockDim.x >> 6);

    const float bb0 = enc_b[lane];
    const float bb1 = enc_b[lane + 64];

    const int P = batch >> 1;           // element pairs

    for (int p = wid; p < P; p += nw) {
        const int e = 2 * p + half;     // this half-wave's element

        float p0 = nb[3 * e], p1 = nb[3 * e + 1], p2 = nb[3 * e + 2];
        float ux = fminf(fmaxf(0.5f + 0.1f * p0, 0.0f), 1.0f) * 40.0f;
        float uy = fminf(fmaxf(0.5f + 0.1f * p1, 0.0f), 1.0f) * 40.0f;
        float uz = fminf(fmaxf(0.5f + 0.1f * p2, 0.0f), 1.0f) * 40.0f;
        int bx = (int)ux, by = (int)uy, bz = (int)uz;
        float wx[4], wy[4], wz[4];
        bspline_w(ux - (float)bx, wx);
        bspline_w(uy - (float)by, wy);
        bspline_w(uz - (float)bz, wz);

        int X[4], Y[4];
#pragma unroll
        for (int o = 0; o < 4; ++o) {
            X[o] = min(max(bx + o - 1, 0), GN - 1) * (GN * GN * CH);
            Y[o] = min(max(by + o - 1, 0), GN - 1) * (GN * CH);
        }
        const int   Zl  = min(max(bz + zsl - 1, 0), GN - 1) * CH + cq;
        const float wzl = wz[zsl];

        float4 acc = make_float4(0.f, 0.f, 0.f, 0.f);
#pragma unroll
        for (int i = 0; i < 4; ++i) {
            float wxi = wx[i];
#pragma unroll
            for (int j = 0; j < 4; ++j) {
                const float4 v =
                    *reinterpret_cast<const float4*>(gT + (X[i] + Y[j] + Zl));
                float w = wxi * wy[j];
                acc.x = fmaf(w, v.x, acc.x);
                acc.y = fmaf(w, v.y, acc.y);
                acc.z = fmaf(w, v.z, acc.z);
                acc.w = fmaf(w, v.w, acc.w);
            }
        }
        acc.x *= wzl; acc.y *= wzl; acc.z *= wzl; acc.w *= wzl;

        // reduce over the 4 z taps (lane bits 3,4) — stays within each half
        acc.x += __shfl_xor(acc.x, 8);  acc.x += __shfl_xor(acc.x, 16);
        acc.y += __shfl_xor(acc.y, 8);  acc.y += __shfl_xor(acc.y, 16);
        acc.z += __shfl_xor(acc.z, 8);  acc.z += __shfl_xor(acc.z, 16);
        acc.w += __shfl_xor(acc.w, 8);  acc.w += __shfl_xor(acc.w, 16);
        // now lane q (resp. 32+q) holds z-summed channels 4q..4q+3 of elem A (B)

        // 32 -> 128 matmul for BOTH elements; weights from LDS, shared A/B
        float oA0 = bb0, oA1 = bb1, oB0 = bb0, oB1 = bb1;
#pragma unroll
        for (int q = 0; q < 8; ++q) {
            float ax = __shfl(acc.x, q),      ay = __shfl(acc.y, q);
            float az = __shfl(acc.z, q),      aw = __shfl(acc.w, q);
            float bx2 = __shfl(acc.x, 32 + q), by2 = __shfl(acc.y, 32 + q);
            float bz2 = __shfl(acc.z, 32 + q), bw2 = __shfl(acc.w, 32 + q);
            const float* wrow = ewT + (4 * q) * EF + lane;
            float e00 = wrow[0],        e01 = wrow[EF];
            float e02 = wrow[2 * EF],   e03 = wrow[3 * EF];
            float e10 = wrow[64],       e11 = wrow[EF + 64];
            float e12 = wrow[2 * EF + 64], e13 = wrow[3 * EF + 64];
            oA0 = fmaf(ax, e00, oA0); oA0 = fmaf(ay, e01, oA0);
            oA0 = fmaf(az, e02, oA0); oA0 = fmaf(aw, e03, oA0);
            oA1 = fmaf(ax, e10, oA1); oA1 = fmaf(ay, e11, oA1);
            oA1 = fmaf(az, e12, oA1); oA1 = fmaf(aw, e13, oA1);
            oB0 = fmaf(bx2, e00, oB0); oB0 = fmaf(by2, e01, oB0);
            oB0 = fmaf(bz2, e02, oB0); oB0 = fmaf(bw2, e03, oB0);
            oB1 = fmaf(bx2, e10, oB1); oB1 = fmaf(by2, e11, oB1);
            oB1 = fmaf(bz2, e12, oB1); oB1 = fmaf(bw2, e13, oB1);
        }

        // coalesced dword stores: lane -> feats lane and lane+64
        const int eA = 2 * p, eB = 2 * p + 1;
        float* outA = out + (size_t)eA * EF;
        float* outB = out + (size_t)eB * EF;
        outA[lane]      = oA0;
        outA[lane + 64] = oA1;
        outB[lane]      = oB0;
        outB[lane + 64] = oB1;
    }
}

extern "C" void kernel_launch(void* const* d_in, const int* in_sizes, int n_in,
                              void* d_out, int out_size, void* d_ws,
                              size_t ws_size, hipStream_t stream) {
    const float* nb   = (const float*)d_in[0];
    const float* grid = (const float*)d_in[1];
    const float* ew   = (const float*)d_in[2];
    const float* eb   = (const float*)d_in[3];
    float*       out  = (float*)d_out;
    float*       gT   = (float*)d_ws;   // VOX*CH*4 = 8.4 MiB

    int batch = in_sizes[0] / 3;

    transpose_grid_k<<<(VOX + 255) / 256, 256, 0, stream>>>(grid, gT);
    lig_main<<<4096, 256, 0, stream>>>(nb, gT, ew, eb, out, batch);
}

// Round 3
// 162.248 us; speedup vs baseline: 1.4383x; 1.4383x over previous
//
#include <hip/hip_runtime.h>
#include <hip/hip_fp16.h>
#include <cstdint>

constexpr int GN   = 41;                // grid points per dim
constexpr int VOX  = GN * GN * GN;      // 68921 spatial points
constexpr int CH   = 32;                // channels
constexpr int EF   = 128;               // encoder features
constexpr int TILE = 64;                // elements per block
constexpr int XPAD = 36;                // LDS row stride (floats), 144B = 16B-aligned

// -------- Pass 1: [C][X][Y][Z] fp32 -> [X][Y][Z][C] fp16 in d_ws ----------
__global__ __launch_bounds__(256) void transpose_grid_k(
    const float* __restrict__ src, __half* __restrict__ dst) {
    int s = blockIdx.x * 256 + threadIdx.x;
    if (s >= VOX) return;
    float v[CH];
#pragma unroll
    for (int c = 0; c < CH; ++c) v[c] = src[c * VOX + s];  // coalesced in s
    uint32_t pk[16];
#pragma unroll
    for (int i = 0; i < 16; ++i) {
        __half2 h = __floats2half2_rn(v[2 * i], v[2 * i + 1]);
        pk[i] = __builtin_bit_cast(uint32_t, h);
    }
    uint4* d4 = reinterpret_cast<uint4*>(dst + (size_t)s * CH);
#pragma unroll
    for (int q = 0; q < 4; ++q)
        d4[q] = make_uint4(pk[4 * q], pk[4 * q + 1], pk[4 * q + 2], pk[4 * q + 3]);
}

__device__ __forceinline__ void bspline_w(float t, float w[4]) {
    float t2 = t * t, t3 = t2 * t;
    const float k = 1.0f / 6.0f;
    w[0] = k * (1.0f - 3.0f * t + 3.0f * t2 - t3);
    w[1] = k * (4.0f - 6.0f * t2 + 3.0f * t3);
    w[2] = k * (1.0f + 3.0f * t + 3.0f * t2 - 3.0f * t3);
    w[3] = k * t3;
}

// -------- Pass 2: tile of 64 elements per block ----------------------------
// Phase 1 (gather): wave w owns elements [w*16, w*16+16) of the tile, as 8
//   pairs. lane = half(1b)|zsl(2b)|cq(3b); each lane loads 4 fp16 channels
//   per (i,j) row -> one 512B dwordx2 per wave instr covering both elements.
//   z-reduction: 8 shfl_xor per pair. Result staged to LDS (1 ds_write_b128).
// Phase 2 (matmul): lane = element, wave = feature quarter (readfirstlane ->
//   wave-uniform weight rows -> s_load + SGPR-operand FMAs; NO shuffles/LDS).
__global__ __launch_bounds__(256, 4) void lig_main(
    const float* __restrict__ nb, const __half* __restrict__ gT,
    const float* __restrict__ enc_w, const float* __restrict__ enc_b,
    float* __restrict__ out, int batch) {

    __shared__ float xs[TILE * XPAD];   // 9216 B: lig_x, padded rows

    const int tid  = threadIdx.x;
    const int lane = tid & 63;
    const int wv   = tid >> 6;          // wave in block, 0..3
    const int ln32 = lane & 31;
    const int half = lane >> 5;
    const int zsl  = ln32 >> 3;         // z tap 0..3
    const int cq   = (ln32 & 7) * 4;    // channel quad (in halves)

    const int base_e = blockIdx.x * TILE;

    // ---------------- Phase 1: interpolate 16 elements per wave ------------
#pragma unroll 1
    for (int pi = 0; pi < 8; ++pi) {
        const int eloc = wv * 16 + pi * 2 + half;
        const int e    = base_e + eloc;

        float p0 = nb[3 * e], p1 = nb[3 * e + 1], p2 = nb[3 * e + 2];
        float ux = fminf(fmaxf(0.5f + 0.1f * p0, 0.0f), 1.0f) * 40.0f;
        float uy = fminf(fmaxf(0.5f + 0.1f * p1, 0.0f), 1.0f) * 40.0f;
        float uz = fminf(fmaxf(0.5f + 0.1f * p2, 0.0f), 1.0f) * 40.0f;
        int bx = (int)ux, by = (int)uy, bz = (int)uz;
        float wx[4], wy[4], wz[4];
        bspline_w(ux - (float)bx, wx);
        bspline_w(uy - (float)by, wy);
        bspline_w(uz - (float)bz, wz);

        int X[4], Y[4];
#pragma unroll
        for (int o = 0; o < 4; ++o) {
            X[o] = min(max(bx + o - 1, 0), GN - 1) * (GN * GN * CH);
            Y[o] = min(max(by + o - 1, 0), GN - 1) * (GN * CH);
        }
        const int   Zl  = min(max(bz + zsl - 1, 0), GN - 1) * CH + cq;
        const float wzl = wz[zsl];

        float4 acc = make_float4(0.f, 0.f, 0.f, 0.f);
#pragma unroll
        for (int i = 0; i < 4; ++i) {
            float wxi = wx[i];
#pragma unroll
            for (int j = 0; j < 4; ++j) {
                uint2 raw = *reinterpret_cast<const uint2*>(gT + (X[i] + Y[j] + Zl));
                float2 f0 = __half22float2(__builtin_bit_cast(__half2, raw.x));
                float2 f1 = __half22float2(__builtin_bit_cast(__half2, raw.y));
                float wt = wxi * wy[j];
                acc.x = fmaf(wt, f0.x, acc.x);
                acc.y = fmaf(wt, f0.y, acc.y);
                acc.z = fmaf(wt, f1.x, acc.z);
                acc.w = fmaf(wt, f1.y, acc.w);
            }
        }
        acc.x *= wzl; acc.y *= wzl; acc.z *= wzl; acc.w *= wzl;

        // reduce over the 4 z taps (lane bits 3,4) — stays within each half
        acc.x += __shfl_xor(acc.x, 8);  acc.x += __shfl_xor(acc.x, 16);
        acc.y += __shfl_xor(acc.y, 8);  acc.y += __shfl_xor(acc.y, 16);
        acc.z += __shfl_xor(acc.z, 8);  acc.z += __shfl_xor(acc.z, 16);
        acc.w += __shfl_xor(acc.w, 8);  acc.w += __shfl_xor(acc.w, 16);
        // lane q (resp 32+q), q=0..7: z-summed channels 4q..4q+3 of elem A (B)

        if (ln32 < 8)
            *reinterpret_cast<float4*>(&xs[eloc * XPAD + (ln32 << 2)]) = acc;
    }
    __syncthreads();

    // ---------------- Phase 2: 32 -> 128 matmul, element-per-lane ----------
    const int e_loc = lane;
    const int fq    = __builtin_amdgcn_readfirstlane(wv);  // wave-uniform
    const int e     = base_e + e_loc;

    float x[CH];
#pragma unroll
    for (int g = 0; g < 8; ++g) {
        float4 v = *reinterpret_cast<const float4*>(&xs[e_loc * XPAD + g * 4]);
        x[4 * g] = v.x; x[4 * g + 1] = v.y; x[4 * g + 2] = v.z; x[4 * g + 3] = v.w;
    }

    const float* wbase = enc_w + fq * 32 * CH;   // uniform -> s_load stream
    const float* bbase = enc_b + fq * 32;
    float*       obase = out + (size_t)e * EF + fq * 32;

#pragma unroll 4
    for (int f = 0; f < 32; ++f) {
        const float* wr = wbase + f * CH;
        float s = bbase[f];
#pragma unroll
        for (int k = 0; k < CH; ++k) s = fmaf(x[k], wr[k], s);
        obase[f] = s;
    }
}

extern "C" void kernel_launch(void* const* d_in, const int* in_sizes, int n_in,
                              void* d_out, int out_size, void* d_ws,
                              size_t ws_size, hipStream_t stream) {
    const float* nb   = (const float*)d_in[0];
    const float* grid = (const float*)d_in[1];
    const float* ew   = (const float*)d_in[2];
    const float* eb   = (const float*)d_in[3];
    float*       out  = (float*)d_out;
    __half*      gTh  = (__half*)d_ws;   // VOX*CH*2 = 4.2 MiB

    int batch = in_sizes[0] / 3;

    transpose_grid_k<<<(VOX + 255) / 256, 256, 0, stream>>>(grid, gTh);
    lig_main<<<batch / TILE, 256, 0, stream>>>(nb, gTh, ew, eb, out, batch);
}

// Round 4
// 144.721 us; speedup vs baseline: 1.6125x; 1.1211x over previous
//
#include <hip/hip_runtime.h>
#include <hip/hip_fp16.h>
#include <cstdint>

constexpr int GN   = 41;                // grid points per dim
constexpr int VOX  = GN * GN * GN;      // 68921 spatial points
constexpr int CH   = 32;                // channels
constexpr int EF   = 128;               // encoder features
constexpr int TILE = 64;                // elements per block
constexpr int XPAD = 36;                // LDS row stride (floats); 144B, 16B-aligned

// -------- Pass 1: [C][X][Y][Z] fp32 -> [X][Y][Z][C] fp16 in d_ws ----------
// thread = (spatial s, channel-octet ck): 8 coalesced strided reads, one
// fully-coalesced uint4 (8xfp16) store. VOX*4 threads = 1077 blocks -> the
// whole chip participates (round-3 version had 270 blocks, ~1 wave/SIMD,
// latency-bound, ~73 us hiding as the constant total-minus-lig_main residual).
__global__ __launch_bounds__(256) void transpose_grid_k(
    const float* __restrict__ src, __half* __restrict__ dst) {
    int idx = blockIdx.x * 256 + threadIdx.x;
    if (idx >= VOX * 4) return;
    int s  = idx >> 2;
    int ck = idx & 3;                   // channel octet
    float v[8];
#pragma unroll
    for (int i = 0; i < 8; ++i) v[i] = src[(ck * 8 + i) * VOX + s];
    uint32_t pk[4];
#pragma unroll
    for (int i = 0; i < 4; ++i) {
        __half2 h = __floats2half2_rn(v[2 * i], v[2 * i + 1]);
        pk[i] = __builtin_bit_cast(uint32_t, h);
    }
    *reinterpret_cast<uint4*>(dst + (size_t)s * CH + ck * 8) =
        make_uint4(pk[0], pk[1], pk[2], pk[3]);
}

__device__ __forceinline__ void bspline_w(float t, float w[4]) {
    float t2 = t * t, t3 = t2 * t;
    const float k = 1.0f / 6.0f;
    w[0] = k * (1.0f - 3.0f * t + 3.0f * t2 - t3);
    w[1] = k * (4.0f - 6.0f * t2 + 3.0f * t3);
    w[2] = k * (1.0f + 3.0f * t + 3.0f * t2 - 3.0f * t3);
    w[3] = k * t3;
}

// -------- Pass 2: tile of 64 elements per block ----------------------------
// Phase 1 (gather): lane = eq(2b)|zsl(2b)|ck(2b). Each lane loads uint4 =
//   8 fp16 channels at one z tap; 16 lanes cover one element's (i,j) row
//   (4z x 32c = 256 B), so each load instruction serves FOUR elements.
//   wz folded into wx. z-reduce = shfl_xor 4,8. One masked 2x ds_write_b128.
// Phase 2 (matmul): lane = element, wave = feature quarter; wave-uniform
//   weight rows -> s_load stream + SGPR-operand v_fma, no shuffles/LDS.
__global__ __launch_bounds__(256, 4) void lig_main(
    const float* __restrict__ nb, const __half* __restrict__ gT,
    const float* __restrict__ enc_w, const float* __restrict__ enc_b,
    float* __restrict__ out, int batch) {

    __shared__ float xs[TILE * XPAD];   // 9216 B

    const int tid  = threadIdx.x;
    const int lane = tid & 63;
    const int wv   = tid >> 6;
    const int eq   = lane >> 4;         // element in quad
    const int zsl  = (lane >> 2) & 3;   // z tap
    const int ck   = (lane & 3) * 8;    // channel octet base

    const int base_e = blockIdx.x * TILE;

    // ---------------- Phase 1: interpolate 16 elements per wave ------------
#pragma unroll 1
    for (int qi = 0; qi < 4; ++qi) {
        const int eloc = wv * 16 + qi * 4 + eq;
        const int e    = base_e + eloc;

        float p0 = nb[3 * e], p1 = nb[3 * e + 1], p2 = nb[3 * e + 2];
        float ux = fminf(fmaxf(0.5f + 0.1f * p0, 0.0f), 1.0f) * 40.0f;
        float uy = fminf(fmaxf(0.5f + 0.1f * p1, 0.0f), 1.0f) * 40.0f;
        float uz = fminf(fmaxf(0.5f + 0.1f * p2, 0.0f), 1.0f) * 40.0f;
        int bx = (int)ux, by = (int)uy, bz = (int)uz;
        float wx[4], wy[4], wz[4];
        bspline_w(ux - (float)bx, wx);
        bspline_w(uy - (float)by, wy);
        bspline_w(uz - (float)bz, wz);

        const float wzl = wz[zsl];      // fold z weight into x weights
#pragma unroll
        for (int o = 0; o < 4; ++o) wx[o] *= wzl;

        int X[4], Y[4];
#pragma unroll
        for (int o = 0; o < 4; ++o) {
            X[o] = min(max(bx + o - 1, 0), GN - 1) * (GN * GN * CH);
            Y[o] = min(max(by + o - 1, 0), GN - 1) * (GN * CH);
        }
        const int Zoff = min(max(bz + zsl - 1, 0), GN - 1) * CH + ck;

        float acc[8];
#pragma unroll
        for (int k = 0; k < 8; ++k) acc[k] = 0.0f;

#pragma unroll
        for (int i = 0; i < 4; ++i) {
#pragma unroll
            for (int j = 0; j < 4; ++j) {
                const uint4 raw =
                    *reinterpret_cast<const uint4*>(gT + (X[i] + Y[j] + Zoff));
                const float wt = wx[i] * wy[j];
                float2 f0 = __half22float2(__builtin_bit_cast(__half2, raw.x));
                float2 f1 = __half22float2(__builtin_bit_cast(__half2, raw.y));
                float2 f2 = __half22float2(__builtin_bit_cast(__half2, raw.z));
                float2 f3 = __half22float2(__builtin_bit_cast(__half2, raw.w));
                acc[0] = fmaf(wt, f0.x, acc[0]);
                acc[1] = fmaf(wt, f0.y, acc[1]);
                acc[2] = fmaf(wt, f1.x, acc[2]);
                acc[3] = fmaf(wt, f1.y, acc[3]);
                acc[4] = fmaf(wt, f2.x, acc[4]);
                acc[5] = fmaf(wt, f2.y, acc[5]);
                acc[6] = fmaf(wt, f3.x, acc[6]);
                acc[7] = fmaf(wt, f3.y, acc[7]);
            }
        }

        // reduce over the 4 z taps (lane bits 2,3)
#pragma unroll
        for (int k = 0; k < 8; ++k) {
            acc[k] += __shfl_xor(acc[k], 4);
            acc[k] += __shfl_xor(acc[k], 8);
        }

        if ((lane & 12) == 0) {         // zsl == 0 lanes hold the sums
            float* dst = xs + eloc * XPAD + ck;
            *reinterpret_cast<float4*>(dst) =
                make_float4(acc[0], acc[1], acc[2], acc[3]);
            *reinterpret_cast<float4*>(dst + 4) =
                make_float4(acc[4], acc[5], acc[6], acc[7]);
        }
    }
    __syncthreads();

    // ---------------- Phase 2: 32 -> 128 matmul, element-per-lane ----------
    const int e_loc = lane;
    const int fq    = __builtin_amdgcn_readfirstlane(wv);  // wave-uniform
    const int e     = base_e + e_loc;

    float x[CH];
#pragma unroll
    for (int g = 0; g < 8; ++g) {
        float4 v = *reinterpret_cast<const float4*>(&xs[e_loc * XPAD + g * 4]);
        x[4 * g] = v.x; x[4 * g + 1] = v.y; x[4 * g + 2] = v.z; x[4 * g + 3] = v.w;
    }

    const float* wbase = enc_w + fq * 32 * CH;   // uniform -> s_load stream
    const float* bbase = enc_b + fq * 32;
    float*       obase = out + (size_t)e * EF + fq * 32;

#pragma unroll 4
    for (int f = 0; f < 32; ++f) {
        const float* wr = wbase + f * CH;
        float s = bbase[f];
#pragma unroll
        for (int k = 0; k < CH; ++k) s = fmaf(x[k], wr[k], s);
        obase[f] = s;
    }
}

extern "C" void kernel_launch(void* const* d_in, const int* in_sizes, int n_in,
                              void* d_out, int out_size, void* d_ws,
                              size_t ws_size, hipStream_t stream) {
    const float* nb   = (const float*)d_in[0];
    const float* grid = (const float*)d_in[1];
    const float* ew   = (const float*)d_in[2];
    const float* eb   = (const float*)d_in[3];
    float*       out  = (float*)d_out;
    __half*      gTh  = (__half*)d_ws;   // VOX*CH*2 = 4.2 MiB

    int batch = in_sizes[0] / 3;

    transpose_grid_k<<<(VOX * 4 + 255) / 256, 256, 0, stream>>>(grid, gTh);
    lig_main<<<batch / TILE, 256, 0, stream>>>(nb, gTh, ew, eb, out, batch);
}

// Round 8
// 130.880 us; speedup vs baseline: 1.7830x; 1.1058x over previous
//
#include <hip/hip_runtime.h>
#include <hip/hip_fp16.h>
#include <cstdint>

constexpr int GN   = 41;                // grid points per dim
constexpr int VOX  = GN * GN * GN;      // 68921 spatial points
constexpr int CH   = 32;                // channels
constexpr int EF   = 128;               // encoder features
constexpr int TILE = 64;                // elements per block
constexpr int XPAD = 36;                // xs row stride (floats); 144B, 16B-aligned

typedef _Float16 h2 __attribute__((ext_vector_type(2)));

__device__ __forceinline__ uint32_t pack_h2(float a, float b) {
    __half2 h = __floats2half2_rn(a, b);
    return __builtin_bit_cast(uint32_t, h);
}

// -------- Pass 1: grid [C][X][Y][Z] fp32 -> [X][Y][Z][C] fp16 (gT)  +  ----
// -------- enc_w fp32 -> packed f16 k-pairs (ewP[f][p], p = k/2) ------------
__global__ __launch_bounds__(256) void prep_k(
    const float* __restrict__ src, const float* __restrict__ enc_w,
    __half* __restrict__ gT, uint32_t* __restrict__ ewP) {
    int idx = blockIdx.x * 256 + threadIdx.x;
    if (idx < VOX * 4) {
        int s  = idx >> 2;
        int ck = idx & 3;
        float v[8];
#pragma unroll
        for (int i = 0; i < 8; ++i) v[i] = src[(ck * 8 + i) * VOX + s];
        *reinterpret_cast<uint4*>(gT + (size_t)s * CH + ck * 8) =
            make_uint4(pack_h2(v[0], v[1]), pack_h2(v[2], v[3]),
                       pack_h2(v[4], v[5]), pack_h2(v[6], v[7]));
    }
    int pid = idx - VOX * 4;
    if (pid >= 0 && pid < 512) {        // pid = f*4 + qq
        int f  = pid >> 2;
        int qq = pid & 3;
        const float* wr = enc_w + f * CH + qq * 8;   // 8 contiguous k
        float4 a = *reinterpret_cast<const float4*>(wr);
        float4 b = *reinterpret_cast<const float4*>(wr + 4);
        // ewP[f*16 + qq*4 + i] = halves (k=qq*8+2i, qq*8+2i+1)
        *reinterpret_cast<uint4*>(ewP + (size_t)pid * 4) =
            make_uint4(pack_h2(a.x, a.y), pack_h2(a.z, a.w),
                       pack_h2(b.x, b.y), pack_h2(b.z, b.w));
    }
}

__device__ __forceinline__ void bspline_w(float t, float w[4]) {
    float t2 = t * t, t3 = t2 * t;
    const float k = 1.0f / 6.0f;
    w[0] = k * (1.0f - 3.0f * t + 3.0f * t2 - t3);
    w[1] = k * (4.0f - 6.0f * t2 + 3.0f * t3);
    w[2] = k * (1.0f + 3.0f * t + 3.0f * t2 - 3.0f * t3);
    w[3] = k * t3;
}

// -------- Pass 2: 64 elements per block (round-4-verified phase 1) ---------
// Phase 1: lane = eq(2b)|zsl(2b)|ck(2b); uint4 = 8 fp16 channels per load
//   (one instr serves 4 elements); fp32 accumulate; z-reduce shfl_xor(4,8);
//   lig_x -> LDS as f32 (verified layout, XPAD=36).
// Phase 2: lane = element, wave = feature quarter (wave-uniform weights ->
//   s_load stream). v_dot2_f32_f16 on prepacked f16 weight pairs halves the
//   FMA instruction count (512 dot2 vs 1024 fma per lane).
__global__ __launch_bounds__(256, 4) void lig_main(
    const float* __restrict__ nb, const __half* __restrict__ gT,
    const uint32_t* __restrict__ ewP, const float* __restrict__ enc_b,
    float* __restrict__ out, int batch) {

    __shared__ __align__(16) float xs[TILE * XPAD];   // 9216 B

    const int tid  = threadIdx.x;
    const int lane = tid & 63;
    const int wv   = tid >> 6;
    const int eq   = lane >> 4;         // element in quad
    const int zsl  = (lane >> 2) & 3;   // z tap
    const int ck   = (lane & 3) * 8;    // channel octet base
    const int base_e = blockIdx.x * TILE;

    // ---------------- Phase 1: interpolate 16 elements per wave ------------
#pragma unroll 1
    for (int qi = 0; qi < 4; ++qi) {
        const int eloc = wv * 16 + qi * 4 + eq;
        const int e    = base_e + eloc;

        float p0 = nb[3 * e], p1 = nb[3 * e + 1], p2 = nb[3 * e + 2];
        float ux = fminf(fmaxf(0.5f + 0.1f * p0, 0.0f), 1.0f) * 40.0f;
        float uy = fminf(fmaxf(0.5f + 0.1f * p1, 0.0f), 1.0f) * 40.0f;
        float uz = fminf(fmaxf(0.5f + 0.1f * p2, 0.0f), 1.0f) * 40.0f;
        int bx = (int)ux, by = (int)uy, bz = (int)uz;
        float wx[4], wy[4], wz[4];
        bspline_w(ux - (float)bx, wx);
        bspline_w(uy - (float)by, wy);
        bspline_w(uz - (float)bz, wz);

        const float wzl = wz[zsl];      // fold z weight into x weights
#pragma unroll
        for (int o = 0; o < 4; ++o) wx[o] *= wzl;

        int X[4], Y[4];
#pragma unroll
        for (int o = 0; o < 4; ++o) {
            X[o] = min(max(bx + o - 1, 0), GN - 1) * (GN * GN * CH);
            Y[o] = min(max(by + o - 1, 0), GN - 1) * (GN * CH);
        }
        const int Zoff = min(max(bz + zsl - 1, 0), GN - 1) * CH + ck;

        float acc[8];
#pragma unroll
        for (int k = 0; k < 8; ++k) acc[k] = 0.0f;

#pragma unroll
        for (int i = 0; i < 4; ++i) {
#pragma unroll
            for (int j = 0; j < 4; ++j) {
                const uint4 raw =
                    *reinterpret_cast<const uint4*>(gT + (X[i] + Y[j] + Zoff));
                const float wt = wx[i] * wy[j];
                float2 f0 = __half22float2(__builtin_bit_cast(__half2, raw.x));
                float2 f1 = __half22float2(__builtin_bit_cast(__half2, raw.y));
                float2 f2 = __half22float2(__builtin_bit_cast(__half2, raw.z));
                float2 f3 = __half22float2(__builtin_bit_cast(__half2, raw.w));
                acc[0] = fmaf(wt, f0.x, acc[0]);
                acc[1] = fmaf(wt, f0.y, acc[1]);
                acc[2] = fmaf(wt, f1.x, acc[2]);
                acc[3] = fmaf(wt, f1.y, acc[3]);
                acc[4] = fmaf(wt, f2.x, acc[4]);
                acc[5] = fmaf(wt, f2.y, acc[5]);
                acc[6] = fmaf(wt, f3.x, acc[6]);
                acc[7] = fmaf(wt, f3.y, acc[7]);
            }
        }

#pragma unroll
        for (int k = 0; k < 8; ++k) {
            acc[k] += __shfl_xor(acc[k], 4);
            acc[k] += __shfl_xor(acc[k], 8);
        }

        if ((lane & 12) == 0) {         // zsl==0 lanes hold the z-sums
            float* dst = xs + eloc * XPAD + ck;
            *reinterpret_cast<float4*>(dst) =
                make_float4(acc[0], acc[1], acc[2], acc[3]);
            *reinterpret_cast<float4*>(dst + 4) =
                make_float4(acc[4], acc[5], acc[6], acc[7]);
        }
    }
    __syncthreads();

    // ---------------- Phase 2: 32 -> 128 matmul via v_dot2_f32_f16 ---------
    const int e_loc = lane;
    const int fq    = __builtin_amdgcn_readfirstlane(wv);  // wave-uniform
    const int e     = base_e + e_loc;

    // pack this element's lig_x into 16 f16 pairs (channels 2p, 2p+1)
    h2 xp[16];
#pragma unroll
    for (int g = 0; g < 8; ++g) {
        float4 v = *reinterpret_cast<const float4*>(&xs[e_loc * XPAD + g * 4]);
        xp[2 * g]     = __builtin_bit_cast(h2, __builtin_amdgcn_cvt_pkrtz(v.x, v.y));
        xp[2 * g + 1] = __builtin_bit_cast(h2, __builtin_amdgcn_cvt_pkrtz(v.z, v.w));
    }

    const uint32_t* wbase = ewP + (size_t)fq * 32 * 16;  // uniform rows
    const float*    bbase = enc_b + fq * 32;
    float*          obase = out + (size_t)e * EF + fq * 32;

#pragma unroll 4
    for (int f = 0; f < 32; ++f) {
        const uint32_t* wr = wbase + f * 16;
        float s = bbase[f];
#pragma unroll
        for (int p = 0; p < 16; ++p)
            s = __builtin_amdgcn_fdot2(xp[p], __builtin_bit_cast(h2, wr[p]),
                                       s, false);
        obase[f] = s;
    }
}

extern "C" void kernel_launch(void* const* d_in, const int* in_sizes, int n_in,
                              void* d_out, int out_size, void* d_ws,
                              size_t ws_size, hipStream_t stream) {
    const float* nb   = (const float*)d_in[0];
    const float* grid = (const float*)d_in[1];
    const float* ew   = (const float*)d_in[2];
    const float* eb   = (const float*)d_in[3];
    float*       out  = (float*)d_out;
    __half*      gTh  = (__half*)d_ws;                       // 4.41 MB
    uint32_t*    ewP  = (uint32_t*)(gTh + (size_t)VOX * CH); // + 8 KB

    int batch = in_sizes[0] / 3;

    int prep_blocks = (VOX * 4 + 512 + 255) / 256;
    prep_k<<<prep_blocks, 256, 0, stream>>>(grid, ew, gTh, ewP);
    lig_main<<<batch / TILE, 256, 0, stream>>>(nb, gTh, ewP, eb, out, batch);
}